// Round 22
// baseline (100.815 us; speedup 1.0000x reference)
//
#include <hip/hip_runtime.h>
#include <math.h>

typedef _Float16 f16;
typedef f16 half8 __attribute__((ext_vector_type(8)));
typedef float f32x4 __attribute__((ext_vector_type(4)));

// Problem sizes: B=4, T=2048, G=8, D=128, V=1024
#define BT 8192
#define NG 8
#define ND 128
#define NV 1024
#define MARGIN  0.08f    // flag threshold (d2-d1)
#define MARGIN3 0.16f    // FULLBIT threshold (d3-d1)
#define BM 64            // token slots per block
#define BN 64            // codes per tile
#define NT 8             // code tiles per block (half of 16: codes split 2x)
#define FULLBIT 0x40000000u

// d_out layout (float32): ids[65536] | quantized_st[8388608] | 3 losses
#define OUT_IDS 0
#define OUT_Q   65536
#define OUT_L   (65536 + 8388608)

// ws float offsets (~5.9 MB)
#define OFF_C2A    0                   // c2 [v*8+g] (recheck)          (8192)
#define OFF_C2B    8192                // c2 [g*NV+v] (gemm)            (8192)
#define OFF_LOSSG  81920               // per-(token,g) loss partial    (65536)
#define OFF_CNT    147456              // [0]=flag count, [1]=tok count (8)
#define OFF_FLAGS  147464              // flag list                     (65536)
#define OFF_CBH    213000              // cbh fp16 swizzled stream      (524288)
#define OFF_PART   (OFF_CBH + 524288)  // loss partials                 (64)
#define OFF_CAND2  (OFF_PART + 64)     // id2 | FULLBIT per flagged idx (65536)
#define OFF_TOKMAP (OFF_CAND2 + 65536) // compacted non-pad tokens      (8192)
#define OFF_P4     (OFF_TOKMAP + 8192) // half partials float4          (524288)
#define OFF_P1     (OFF_P4 + 524288)   // half partials d3              (131072)

// ---------------------------------------------------------------------------
__device__ __forceinline__ void gll16(const f16* g, f16* l) {
    __builtin_amdgcn_global_load_lds(
        (const __attribute__((address_space(1))) unsigned int*)g,
        (__attribute__((address_space(3))) unsigned int*)l, 16, 0, 0);
}

// ---------------------------------------------------------------------------
// prep (blocks 0-511): c2 both layouts (R1-exact) + pre-swizzled fp16
// codebook stream. Block 512: deterministic token compaction (prefix sum,
// sorted tokmap), writes cnt[1]=token count (== msum) and cnt[0]=0.
// ---------------------------------------------------------------------------
__global__ __launch_bounds__(256) void prep_kernel(
    const float* __restrict__ cb, const int* __restrict__ pad,
    f16* __restrict__ cbh, float* __restrict__ c2a, float* __restrict__ c2b,
    int* __restrict__ cnt, int* __restrict__ tokmap) {
    const int tid = threadIdx.x;
    if (blockIdx.x == 512) {              // compaction block
        __shared__ int ps[256];
        const int base = tid * 32;
        int c = 0;
#pragma unroll
        for (int i = 0; i < 32; ++i) c += 1 - pad[base + i];
        ps[tid] = c;
        __syncthreads();
        for (int st = 1; st < 256; st <<= 1) {
            int v = (tid >= st) ? ps[tid - st] : 0;
            __syncthreads();
            ps[tid] += v;
            __syncthreads();
        }
        int o = ps[tid] - c;
        if (tid == 255) {
            cnt[1] = ps[255];
            cnt[0] = 0;
        }
        for (int i = 0; i < 32; ++i) {
            int tok = base + i;
            if (!pad[tok]) tokmap[o++] = tok;
        }
        return;
    }

    __shared__ float prod[16][16][9];
    __shared__ float rbuf[16][8];
    const int rloc = tid >> 4, t = tid & 15;
    const int idx = blockIdx.x * 16 + rloc;   // cb row = v*8+g
    const int v = idx >> 3, g = idx & 7;
    const int rl = v & 63;
    const float4* row4 = (const float4*)(cb + (size_t)idx * ND);

    float4 a = row4[t * 2], b = row4[t * 2 + 1];
    float vv[8] = {a.x, a.y, a.z, a.w, b.x, b.y, b.z, b.w};
    half8 h;
#pragma unroll
    for (int e = 0; e < 8; ++e) {
        prod[rloc][t][e] = __fmul_rn(vv[e], vv[e]);
        h[e] = (f16)vv[e];
    }
    int cn = v >> 6;
    size_t base = ((size_t)(g * 16 + cn)) * 8192 + rl * 128;
    *(half8*)(cbh + base + ((t ^ (rl & 7)) * 8)) = h;
    __syncthreads();

    if (t < 8) {
        float r = 0.f;
#pragma unroll
        for (int tt = 0; tt < 16; ++tt)
            r = __fadd_rn(r, prod[rloc][tt][t]);
        rbuf[rloc][t] = r;
    }
    __syncthreads();
    if (t == 0) {
        float s = __fadd_rn(
            __fadd_rn(__fadd_rn(rbuf[rloc][0], rbuf[rloc][1]),
                      __fadd_rn(rbuf[rloc][2], rbuf[rloc][3])),
            __fadd_rn(__fadd_rn(rbuf[rloc][4], rbuf[rloc][5]),
                      __fadd_rn(rbuf[rloc][6], rbuf[rloc][7])));
        c2a[idx] = s;
        c2b[g * NV + v] = s;
    }
}

// ---------------------------------------------------------------------------
// padfill, grid-stride (512 blocks): padded tokens get q=0, ids=-1, loss=0.
// ---------------------------------------------------------------------------
__global__ __launch_bounds__(256) void padfill(
    const int* __restrict__ pad, float* __restrict__ out_ids,
    float* __restrict__ out_q, float* __restrict__ lossg) {
    const int gt = blockIdx.x * 256 + threadIdx.x;
    const float4 z = make_float4(0.f, 0.f, 0.f, 0.f);
#pragma unroll 4
    for (int i = gt; i < BT * NG * ND / 4; i += 512 * 256) {
        int tok = i >> 8;
        if (pad[tok]) ((float4*)out_q)[i] = z;
    }
    if (gt < BT * NG) {
        int tok = gt >> 3;
        if (pad[tok]) {
            out_ids[gt] = -1.0f;
            lossg[gt] = 0.0f;
        }
    }
}

// ---------------------------------------------------------------------------
// MFMA distance GEMM, CODE-SPLIT: block = (tile, g, half); 64 token slots x
// 512 codes (8 tiles). Grid 2048 -> ~1024 active blocks = 4/CU (R21 was 2).
// Total staging and MFMA identical to R21 (codes split, tokens not).
// Per-(token,code) arithmetic bitwise unchanged. Emits sorted top-3 partial
// (d1,i1,d2,i2,d3) per (slot,g,half) to part; merge kernel finishes.
// ---------------------------------------------------------------------------
__global__ __launch_bounds__(256, 4) void mfma_gemm(
    const float* __restrict__ x, const f16* __restrict__ cbh,
    const float* __restrict__ c2b, const int* __restrict__ ncnt,
    const int* __restrict__ tokmap, float4* __restrict__ part4,
    float* __restrict__ part1) {
    __shared__ __align__(16) f16 Bh[2][BN * ND];   // 2 x 16 KB
    __shared__ __align__(16) float c2s[NV];        // 4 KB

    const int tid = threadIdx.x;
    const int b = blockIdx.x;
    const int h = b & 1;                     // code half
    const int g = (b >> 1) & 7;
    const int count = *ncnt;
    const int tile_base = (b >> 4) * BM;
    if (tile_base >= count) return;
    const int lane = tid & 63;
    const int w = tid >> 6;
    const int wr = w & 1, wc = w >> 1;
    const int l15 = lane & 15, l4 = lane >> 4;

    // prologue: c2 -> LDS, issue tile-0 DMA, A load/convert under it
    ((float4*)c2s)[tid] = ((const float4*)(c2b + (size_t)g * NV))[tid];
    {
        const f16* sh = cbh + ((size_t)(g * 16 + h * 8)) * 8192;
#pragma unroll
        for (int it = 0; it < 4; ++it)
            gll16(sh + it * 2048 + tid * 8, &Bh[0][it * 2048 + tid * 8]);
    }

    int tokA_[2];
#pragma unroll
    for (int ti = 0; ti < 2; ++ti) {
        int slot = tile_base + wr * 32 + ti * 16 + l15;
        tokA_[ti] = tokmap[(slot < count) ? slot : 0];
    }

    half8 ah[4][2];   // [kk][ti]
#pragma unroll
    for (int kk = 0; kk < 4; ++kk)
#pragma unroll
        for (int ti = 0; ti < 2; ++ti) {
            const float* ap = x + ((size_t)tokA_[ti] * NG + g) * ND
                              + kk * 32 + l4 * 8;
            float4 p0 = *(const float4*)ap, p1 = *(const float4*)(ap + 4);
            float vv[8] = {p0.x, p0.y, p0.z, p0.w, p1.x, p1.y, p1.z, p1.w};
            half8 hh;
#pragma unroll
            for (int j = 0; j < 8; ++j) hh[j] = (f16)vv[j];
            ah[kk][ti] = hh;
        }

    float d1s[2][4], d2s[2][4], d3s[2][4];
    int id1s[2][4], id2s[2][4];
#pragma unroll
    for (int ti = 0; ti < 2; ++ti)
#pragma unroll
        for (int r = 0; r < 4; ++r) {
            d1s[ti][r] = INFINITY;
            d2s[ti][r] = INFINITY;
            d3s[ti][r] = INFINITY;
            id1s[ti][r] = 0;
            id2s[ti][r] = 0;
        }

    int buf = 0;
#pragma unroll 1
    for (int t = 0; t < NT; ++t) {
        asm volatile("s_waitcnt vmcnt(0) lgkmcnt(0)" ::: "memory");
        __builtin_amdgcn_s_barrier();
        __builtin_amdgcn_sched_barrier(0);

        if (t + 1 < NT) {
            const f16* sh = cbh + ((size_t)(g * 16 + h * 8 + t + 1)) * 8192;
#pragma unroll
            for (int it = 0; it < 4; ++it)
                gll16(sh + it * 2048 + tid * 8,
                      &Bh[buf ^ 1][it * 2048 + tid * 8]);
        }

        f32x4 acc[2][2];
#pragma unroll
        for (int ti = 0; ti < 2; ++ti)
#pragma unroll
            for (int tj = 0; tj < 2; ++tj)
                acc[ti][tj] = (f32x4){0.f, 0.f, 0.f, 0.f};

#pragma unroll
        for (int kk = 0; kk < 4; ++kk) {
            half8 bh[2];
#pragma unroll
            for (int tj = 0; tj < 2; ++tj) {
                int rw = wc * 32 + tj * 16 + l15;
                bh[tj] = *(const half8*)(
                    &Bh[buf][rw * 128 + (((kk * 4 + l4) ^ (rw & 7)) << 3)]);
            }
#pragma unroll
            for (int ti = 0; ti < 2; ++ti)
#pragma unroll
                for (int tj = 0; tj < 2; ++tj)
                    acc[ti][tj] = __builtin_amdgcn_mfma_f32_16x16x32_f16(
                        ah[kk][ti], bh[tj], acc[ti][tj], 0, 0, 0);
        }

        // epilogue: exact sorted top-3 (ids for top-2)
#pragma unroll
        for (int tj = 0; tj < 2; ++tj) {
            int code = h * 512 + t * BN + wc * 32 + tj * 16 + l15;
            float c2v = c2s[code];
#pragma unroll
            for (int ti = 0; ti < 2; ++ti)
#pragma unroll
                for (int r = 0; r < 4; ++r) {
                    float dv = fmaf(-2.0f, acc[ti][tj][r], c2v);
                    bool lt1 = dv < d1s[ti][r];
                    bool lt2 = dv < d2s[ti][r];
                    bool lt3 = dv < d3s[ti][r];
                    d3s[ti][r] = lt2 ? d2s[ti][r] : (lt3 ? dv : d3s[ti][r]);
                    d2s[ti][r] = lt1 ? d1s[ti][r] : (lt2 ? dv : d2s[ti][r]);
                    id2s[ti][r] = lt1 ? id1s[ti][r] : (lt2 ? code : id2s[ti][r]);
                    d1s[ti][r] = lt1 ? dv : d1s[ti][r];
                    id1s[ti][r] = lt1 ? code : id1s[ti][r];
                }
        }
        buf ^= 1;
    }

    // merge: butterfly over l15 (sorted triples), then across wc via LDS
    __syncthreads();
    float4* red = (float4*)&Bh[0][0];            // 128 x float4
    float* redd3 = (float*)(red + 128);          // 128 x float
#pragma unroll
    for (int ti = 0; ti < 2; ++ti)
#pragma unroll
        for (int r = 0; r < 4; ++r) {
            float d1 = d1s[ti][r], d2 = d2s[ti][r], d3 = d3s[ti][r];
            int i1 = id1s[ti][r], i2 = id2s[ti][r];
#pragma unroll
            for (int m = 1; m < 16; m <<= 1) {
                float od1 = __shfl_xor(d1, m);
                float od2 = __shfl_xor(d2, m);
                float od3 = __shfl_xor(d3, m);
                int oi1 = __shfl_xor(i1, m);
                int oi2 = __shfl_xor(i2, m);
                bool ow = od1 < d1;
                float w1 = ow ? od1 : d1, w2 = ow ? od2 : d2, w3 = ow ? od3 : d3;
                int wi1 = ow ? oi1 : i1, wi2 = ow ? oi2 : i2;
                float l1 = ow ? d1 : od1, l2 = ow ? d2 : od2;
                int li1 = ow ? i1 : oi1;
                d1 = w1; i1 = wi1;
                bool t2 = w2 < l1;
                d2 = t2 ? w2 : l1;
                i2 = t2 ? wi2 : li1;
                d3 = t2 ? fminf(w3, l1) : fminf(w2, l2);
            }
            if (l15 == 0) {
                int o = wc * BM + wr * 32 + ti * 16 + l4 * 4 + r;
                red[o] = make_float4(d1, __int_as_float(i1), d2,
                                     __int_as_float(i2));
                redd3[o] = d3;
            }
        }
    __syncthreads();

    if (tid < BM) {
        float4 A = red[tid], C = red[BM + tid];
        float a3 = redd3[tid], c3 = redd3[BM + tid];
        bool cw = C.x < A.x;
        float w1 = cw ? C.x : A.x, w2 = cw ? C.z : A.z, w3 = cw ? c3 : a3;
        int wi1 = cw ? __float_as_int(C.y) : __float_as_int(A.y);
        int wi2 = cw ? __float_as_int(C.w) : __float_as_int(A.w);
        float l1 = cw ? A.x : C.x, l2 = cw ? A.z : C.z;
        int li1 = cw ? __float_as_int(A.y) : __float_as_int(C.y);
        float d1 = w1;
        int i1 = wi1;
        bool t2 = w2 < l1;
        float d2 = t2 ? w2 : l1;
        int i2 = t2 ? wi2 : li1;
        float d3 = t2 ? fminf(w3, l1) : fminf(w2, l2);

        int slot = tile_base + tid;
        if (slot < count) {
            int o = slot * 16 + g * 2 + h;
            part4[o] = make_float4(d1, __int_as_float(i1), d2,
                                   __int_as_float(i2));
            part1[o] = d3;
        }
    }
}

// ---------------------------------------------------------------------------
// merge_kernel: merge the two code-half partials per (slot,g); write ids,
// flags, cand2; fused gather + exact loss (same math as R21 gemm tail).
// Block = 32 slots x 8 g. Grid 256.
// ---------------------------------------------------------------------------
__global__ __launch_bounds__(256) void merge_kernel(
    const float* __restrict__ x, const float* __restrict__ cb,
    const int* __restrict__ ncnt, const int* __restrict__ tokmap,
    const float4* __restrict__ part4, const float* __restrict__ part1,
    float* __restrict__ out_ids, float* __restrict__ out_q,
    float* __restrict__ lossg, int* __restrict__ cnt,
    int* __restrict__ flags, int* __restrict__ cand2) {
    __shared__ int idsM[256];
    __shared__ int tokM[32];
    const int tid = threadIdx.x;
    const int count = *ncnt;
    const int sbase = blockIdx.x * 32;
    if (sbase >= count) return;
    const int sl = tid >> 3, g = tid & 7;
    const int slot = sbase + sl;

    if (tid < 32)
        tokM[tid] = (sbase + tid < count) ? tokmap[sbase + tid] : -1;

    if (slot < count) {
        int o0 = slot * 16 + g * 2;
        float4 A = part4[o0], C = part4[o0 + 1];
        float a3 = part1[o0], c3 = part1[o0 + 1];
        bool cw = C.x < A.x;
        float w1 = cw ? C.x : A.x, w2 = cw ? C.z : A.z, w3 = cw ? c3 : a3;
        int wi1 = cw ? __float_as_int(C.y) : __float_as_int(A.y);
        int wi2 = cw ? __float_as_int(C.w) : __float_as_int(A.w);
        float l1 = cw ? A.x : C.x, l2 = cw ? A.z : C.z;
        int li1 = cw ? __float_as_int(A.y) : __float_as_int(C.y);
        float d1 = w1;
        int i1 = wi1;
        bool t2 = w2 < l1;
        float d2 = t2 ? w2 : l1;
        int i2 = t2 ? wi2 : li1;
        float d3 = t2 ? fminf(w3, l1) : fminf(w2, l2);

        int tok = tokmap[slot];
        int idx = tok * NG + g;
        out_ids[idx] = (float)i1;
        idsM[tid] = i1;
        if (d2 - d1 < MARGIN) {
            int pos = atomicAdd(cnt, 1);
            flags[pos] = idx;
            cand2[idx] = i2 | ((d3 - d1 < MARGIN3) ? (int)FULLBIT : 0);
        }
    } else {
        idsM[tid] = -1;
    }
    __syncthreads();

    // gather + exact loss: 256 rows (sl*8+g) x 32 float4
#pragma unroll 1
    for (int it = 0; it < 32; ++it) {
        int i = it * 256 + tid;
        int r = i >> 5, d4 = i & 31;
        int id = idsM[r];
        if (id >= 0) {
            int tok = tokM[r >> 3];
            int gg = r & 7;
            size_t rowo = ((size_t)tok * NG + gg) * ND;
            float4 q = ((const float4*)(cb + ((size_t)id * NG + gg) * ND))[d4];
            float4 a = ((const float4*)(x + rowo))[d4];
            float e0 = q.x - a.x, e1 = q.y - a.y;
            float e2 = q.z - a.z, e3 = q.w - a.w;
            float s = e0 * e0 + e1 * e1 + e2 * e2 + e3 * e3;
            ((float4*)(out_q + rowo))[d4] = q;
#pragma unroll
            for (int m = 1; m < 32; m <<= 1) s += __shfl_xor(s, m);
            if (d4 == 0) lossg[tok * NG + gg] = s;
        }
    }
}

// ---------------------------------------------------------------------------
// recheck: pass 1 wave-per-flag 2-candidate compare; pass 2 full scan.
// ---------------------------------------------------------------------------
__global__ __launch_bounds__(256) void recheck(
    const float* __restrict__ x, const float* __restrict__ cb,
    const float* __restrict__ c2w, const int* __restrict__ cnt,
    const int* __restrict__ flags, const int* __restrict__ cand2,
    float* __restrict__ out_ids, float* __restrict__ out_q,
    float* __restrict__ lossg) {
    __shared__ __align__(16) float xs[ND];
    __shared__ float2 redw[4];
    __shared__ int bidS;
    const int tid = threadIdx.x;
    const int lane = tid & 63;
    const int w = tid >> 6;
    const int n_f = cnt[0];

    for (int f = blockIdx.x * 4 + w; f < n_f; f += gridDim.x * 4) {
        int idx = flags[f];
        unsigned cc = (unsigned)cand2[idx];
        if (cc & FULLBIT) continue;
        int g = idx & 7;
        int id1 = (int)out_ids[idx];
        int id2 = (int)(cc & ~FULLBIT);
        float2 xv = ((const float2*)(x + (size_t)idx * ND))[lane];
        float2 av = ((const float2*)(cb + ((size_t)id1 * NG + g) * ND))[lane];
        float2 bv = ((const float2*)(cb + ((size_t)id2 * NG + g) * ND))[lane];
        float eA0 = xv.x - av.x, eA1 = xv.y - av.y;
        float eB0 = xv.x - bv.x, eB1 = xv.y - bv.y;
        float sA = eA0 * eA0 + eA1 * eA1;
        float sB = eB0 * eB0 + eB1 * eB1;
#pragma unroll
        for (int m = 1; m < 64; m <<= 1) {
            sA += __shfl_xor(sA, m);
            sB += __shfl_xor(sB, m);
        }
        int win;
        float sw;
        if (sA < sB) { win = id1; sw = sA; }
        else if (sB < sA) { win = id2; sw = sB; }
        else { win = (id1 < id2) ? id1 : id2; sw = sA; }
        if (win != id1) {
            if (lane == 0) {
                out_ids[idx] = (float)win;
                lossg[idx] = sw;
            }
            if (lane < 32) {
                float4 q = ((const float4*)(cb + ((size_t)win * NG + g) * ND))[lane];
                ((float4*)(out_q + (size_t)idx * ND))[lane] = q;
            }
        }
    }
    __syncthreads();

    for (int f = blockIdx.x; f < n_f; f += gridDim.x) {
        int idx = flags[f];
        if (!(((unsigned)cand2[idx]) & FULLBIT)) continue;
        int g = idx & 7;
        __syncthreads();
        if (tid < 32)
            ((float4*)xs)[tid] = ((const float4*)(x + (size_t)idx * ND))[tid];
        __syncthreads();

        float rr[8];
#pragma unroll
        for (int j = 0; j < 8; ++j) rr[j] = 0.0f;
#pragma unroll
        for (int i = 0; i < 32; ++i) {
            float4 v = ((const float4*)xs)[i];
            int j0 = (i * 4) & 7;
            rr[j0 + 0] = __fadd_rn(rr[j0 + 0], __fmul_rn(v.x, v.x));
            rr[j0 + 1] = __fadd_rn(rr[j0 + 1], __fmul_rn(v.y, v.y));
            rr[j0 + 2] = __fadd_rn(rr[j0 + 2], __fmul_rn(v.z, v.z));
            rr[j0 + 3] = __fadd_rn(rr[j0 + 3], __fmul_rn(v.w, v.w));
        }
        float x2v = __fadd_rn(
            __fadd_rn(__fadd_rn(rr[0], rr[1]), __fadd_rn(rr[2], rr[3])),
            __fadd_rn(__fadd_rn(rr[4], rr[5]), __fadd_rn(rr[6], rr[7])));

        float best = INFINITY;
        int bid = 0x7FFFFFFF;
        float s0 = 0.f, s1 = 0.f, s2 = 0.f, s3 = 0.f;
#pragma unroll
        for (int i = 0; i < 32; ++i) {
            float4 a = ((const float4*)xs)[i];
            float4 q0 = ((const float4*)(cb + ((size_t)(tid) * NG + g) * ND))[i];
            float4 q1 = ((const float4*)(cb + ((size_t)(tid + 256) * NG + g) * ND))[i];
            float4 q2 = ((const float4*)(cb + ((size_t)(tid + 512) * NG + g) * ND))[i];
            float4 q3 = ((const float4*)(cb + ((size_t)(tid + 768) * NG + g) * ND))[i];
            s0 = fmaf(a.x, q0.x, s0); s0 = fmaf(a.y, q0.y, s0);
            s0 = fmaf(a.z, q0.z, s0); s0 = fmaf(a.w, q0.w, s0);
            s1 = fmaf(a.x, q1.x, s1); s1 = fmaf(a.y, q1.y, s1);
            s1 = fmaf(a.z, q1.z, s1); s1 = fmaf(a.w, q1.w, s1);
            s2 = fmaf(a.x, q2.x, s2); s2 = fmaf(a.y, q2.y, s2);
            s2 = fmaf(a.z, q2.z, s2); s2 = fmaf(a.w, q2.w, s2);
            s3 = fmaf(a.x, q3.x, s3); s3 = fmaf(a.y, q3.y, s3);
            s3 = fmaf(a.z, q3.z, s3); s3 = fmaf(a.w, q3.w, s3);
        }
        float dd[4] = {s0, s1, s2, s3};
#pragma unroll
        for (int jj = 0; jj < 4; ++jj) {
            int c = tid + 256 * jj;
            float d = __fadd_rn(__fsub_rn(x2v, __fmul_rn(2.0f, dd[jj])),
                                c2w[(size_t)c * NG + g]);
            if (d < best || (d == best && c < bid)) { best = d; bid = c; }
        }
#pragma unroll
        for (int m = 1; m < 64; m <<= 1) {
            float od = __shfl_xor(best, m);
            int ob = __shfl_xor(bid, m);
            if (od < best || (od == best && ob < bid)) { best = od; bid = ob; }
        }
        if (lane == 0) redw[w] = make_float2(best, __int_as_float(bid));
        __syncthreads();
        if (tid == 0) {
            float b2 = redw[0].x;
            int i2 = __float_as_int(redw[0].y);
#pragma unroll
            for (int ww = 1; ww < 4; ++ww) {
                float ob = redw[ww].x;
                int oi = __float_as_int(redw[ww].y);
                if (ob < b2 || (ob == b2 && oi < i2)) { b2 = ob; i2 = oi; }
            }
            out_ids[idx] = (float)i2;
            bidS = i2;
        }
        __syncthreads();
        if (tid < 32) {
            float4 q = ((const float4*)(cb + ((size_t)bidS * NG + g) * ND))[tid];
            ((float4*)(out_q + (size_t)idx * ND))[tid] = q;
            float4 a = ((const float4*)xs)[tid];
            float e0 = q.x - a.x, e1 = q.y - a.y;
            float e2 = q.z - a.z, e3 = q.w - a.w;
            float s = e0 * e0 + e1 * e1 + e2 * e2 + e3 * e3;
#pragma unroll
            for (int m = 1; m < 32; m <<= 1) s += __shfl_xor(s, m);
            if (tid == 0) lossg[idx] = s;
        }
    }
}

// ---------------------------------------------------------------------------
__global__ __launch_bounds__(256) void loss_part(
    const float* __restrict__ lossg, float* __restrict__ part) {
    __shared__ float sr[256];
    const int tid = threadIdx.x;
    float4 v = ((const float4*)lossg)[blockIdx.x * 256 + tid];
    sr[tid] = ((v.x + v.y) + (v.z + v.w));
    __syncthreads();
    for (int st = 128; st > 0; st >>= 1) {
        if (tid < st) sr[tid] += sr[tid + st];
        __syncthreads();
    }
    if (tid == 0) part[blockIdx.x] = sr[0];
}

// ---------------------------------------------------------------------------
// final: msum = cnt[1] (token count from compaction); 64-lane tree sum.
// ---------------------------------------------------------------------------
__global__ __launch_bounds__(64) void final_kernel(
    const int* __restrict__ cnt, const float* __restrict__ part,
    float* __restrict__ out_l) {
    const int tid = threadIdx.x;
    float s = part[tid];
#pragma unroll
    for (int m = 1; m < 64; m <<= 1) s += __shfl_xor(s, m);
    if (tid == 0) {
        float k = s / (float)cnt[1];
        out_l[0] = k;
        out_l[1] = k;
        out_l[2] = k + k;
    }
}

// ---------------------------------------------------------------------------
extern "C" void kernel_launch(void* const* d_in, const int* in_sizes, int n_in,
                              void* d_out, int out_size, void* d_ws, size_t ws_size,
                              hipStream_t stream) {
    const float* x = (const float*)d_in[0];
    const int* pad = (const int*)d_in[1];
    const float* cb = (const float*)d_in[2];
    float* out = (float*)d_out;
    float* ws = (float*)d_ws;

    float* ws_c2a = ws + OFF_C2A;
    float* ws_c2b = ws + OFF_C2B;
    float* ws_lossg = ws + OFF_LOSSG;
    int* ws_cnt = (int*)(ws + OFF_CNT);
    int* ws_flags = (int*)(ws + OFF_FLAGS);
    f16* cbh = (f16*)(ws + OFF_CBH);
    float* ws_part = ws + OFF_PART;
    int* ws_cand2 = (int*)(ws + OFF_CAND2);
    int* ws_tokmap = (int*)(ws + OFF_TOKMAP);
    float4* ws_p4 = (float4*)(ws + OFF_P4);
    float* ws_p1 = ws + OFF_P1;

    prep_kernel<<<513, 256, 0, stream>>>(cb, pad, cbh, ws_c2a, ws_c2b,
                                         ws_cnt, ws_tokmap);
    padfill<<<512, 256, 0, stream>>>(pad, out + OUT_IDS, out + OUT_Q, ws_lossg);
    mfma_gemm<<<(BT / BM) * NG * 2, 256, 0, stream>>>(x, cbh, ws_c2b,
                                                      ws_cnt + 1, ws_tokmap,
                                                      ws_p4, ws_p1);
    merge_kernel<<<256, 256, 0, stream>>>(x, cb, ws_cnt + 1, ws_tokmap,
                                          ws_p4, ws_p1, out + OUT_IDS,
                                          out + OUT_Q, ws_lossg, ws_cnt,
                                          ws_flags, ws_cand2);
    recheck<<<512, 256, 0, stream>>>(x, cb, ws_c2a, ws_cnt, ws_flags,
                                     ws_cand2, out + OUT_IDS, out + OUT_Q,
                                     ws_lossg);
    loss_part<<<64, 256, 0, stream>>>(ws_lossg, ws_part);
    final_kernel<<<1, 64, 0, stream>>>(ws_cnt, ws_part, out + OUT_L);
}

// Round 23
// 73.975 us; speedup vs baseline: 1.3628x; 1.3628x over previous
//
#include <hip/hip_runtime.h>
#include <math.h>

typedef _Float16 f16;
typedef f16 half8 __attribute__((ext_vector_type(8)));
typedef float f32x4 __attribute__((ext_vector_type(4)));

// Problem sizes: B=4, T=2048, G=8, D=128, V=1024
#define BT 8192
#define NG 8
#define ND 128
#define NV 1024
#define MARGIN  0.08f    // flag threshold (d2-d1)
#define MARGIN3 0.16f    // FULLBIT threshold (d3-d1)
#define BM 64            // token slots per block (R19/R21-proven)
#define BN 64            // codes per tile
#define NT 16            // code tiles
#define FULLBIT 0x40000000u

// d_out layout (float32): ids[65536] | quantized_st[8388608] | 3 losses
#define OUT_IDS 0
#define OUT_Q   65536
#define OUT_L   (65536 + 8388608)

// ws float offsets (~3.4 MB)
#define OFF_C2A    0                   // c2 [v*8+g] (recheck)          (8192)
#define OFF_C2B    8192                // c2 [g*NV+v] (gemm)            (8192)
#define OFF_LOSSG  81920               // per-(token,g) loss partial    (65536)
#define OFF_CNT    147456              // [0]=flag count, [1]=tok count (8)
#define OFF_FLAGS  147464              // flag list                     (65536)
#define OFF_CBH    213000              // cbh fp16 swizzled stream      (524288)
#define OFF_PART   (OFF_CBH + 524288)  // loss partials                 (64)
#define OFF_CAND2  (OFF_PART + 64)     // id2 | FULLBIT per flagged idx (65536)
#define OFF_TOKMAP (OFF_CAND2 + 65536) // compacted non-pad tokens      (8192)

// ---------------------------------------------------------------------------
__device__ __forceinline__ void gll16(const f16* g, f16* l) {
    __builtin_amdgcn_global_load_lds(
        (const __attribute__((address_space(1))) unsigned int*)g,
        (__attribute__((address_space(3))) unsigned int*)l, 16, 0, 0);
}

// ---------------------------------------------------------------------------
// prep (fused, 1025 blocks):
//   blocks 0-511 : c2 both layouts (R1-exact) + pre-swizzled fp16 cb stream
//   block  512   : deterministic token compaction (prefix sum, sorted
//                  tokmap); writes cnt[1]=token count, cnt[0]=0
//   blocks 513+  : padfill (padded tokens: q=0, ids=-1, loss=0)
// ---------------------------------------------------------------------------
__global__ __launch_bounds__(256) void prep_kernel(
    const float* __restrict__ cb, const int* __restrict__ pad,
    f16* __restrict__ cbh, float* __restrict__ c2a, float* __restrict__ c2b,
    int* __restrict__ cnt, int* __restrict__ tokmap,
    float* __restrict__ out_ids, float* __restrict__ out_q,
    float* __restrict__ lossg) {
    const int tid = threadIdx.x;

    if (blockIdx.x == 512) {              // compaction block
        __shared__ int ps[256];
        const int base = tid * 32;
        int c = 0;
#pragma unroll
        for (int i = 0; i < 32; ++i) c += 1 - pad[base + i];
        ps[tid] = c;
        __syncthreads();
        for (int st = 1; st < 256; st <<= 1) {
            int v = (tid >= st) ? ps[tid - st] : 0;
            __syncthreads();
            ps[tid] += v;
            __syncthreads();
        }
        int o = ps[tid] - c;
        if (tid == 255) {
            cnt[1] = ps[255];
            cnt[0] = 0;
        }
        for (int i = 0; i < 32; ++i) {
            int tok = base + i;
            if (!pad[tok]) tokmap[o++] = tok;
        }
        return;
    }

    if (blockIdx.x > 512) {               // padfill blocks (512 of them)
        const int gt = (blockIdx.x - 513) * 256 + tid;   // 131072 threads
        const float4 z = make_float4(0.f, 0.f, 0.f, 0.f);
#pragma unroll 4
        for (int i = gt; i < BT * NG * ND / 4; i += 512 * 256) {
            int tok = i >> 8;             // 256 float4 per token
            if (pad[tok]) ((float4*)out_q)[i] = z;
        }
        if (gt < BT * NG) {
            int tok = gt >> 3;
            if (pad[tok]) {
                out_ids[gt] = -1.0f;
                lossg[gt] = 0.0f;
            }
        }
        return;
    }

    __shared__ float prod[16][16][9];
    __shared__ float rbuf[16][8];
    const int rloc = tid >> 4, t = tid & 15;
    const int idx = blockIdx.x * 16 + rloc;   // cb row = v*8+g
    const int v = idx >> 3, g = idx & 7;
    const int rl = v & 63;
    const float4* row4 = (const float4*)(cb + (size_t)idx * ND);

    float4 a = row4[t * 2], b = row4[t * 2 + 1];
    float vv[8] = {a.x, a.y, a.z, a.w, b.x, b.y, b.z, b.w};
    half8 h;
#pragma unroll
    for (int e = 0; e < 8; ++e) {
        prod[rloc][t][e] = __fmul_rn(vv[e], vv[e]);
        h[e] = (f16)vv[e];
    }
    int cn = v >> 6;
    size_t base = ((size_t)(g * 16 + cn)) * 8192 + rl * 128;
    *(half8*)(cbh + base + ((t ^ (rl & 7)) * 8)) = h;
    __syncthreads();

    if (t < 8) {
        float r = 0.f;
#pragma unroll
        for (int tt = 0; tt < 16; ++tt)
            r = __fadd_rn(r, prod[rloc][tt][t]);
        rbuf[rloc][t] = r;
    }
    __syncthreads();
    if (t == 0) {
        float s = __fadd_rn(
            __fadd_rn(__fadd_rn(rbuf[rloc][0], rbuf[rloc][1]),
                      __fadd_rn(rbuf[rloc][2], rbuf[rloc][3])),
            __fadd_rn(__fadd_rn(rbuf[rloc][4], rbuf[rloc][5]),
                      __fadd_rn(rbuf[rloc][6], rbuf[rloc][7])));
        c2a[idx] = s;
        c2b[g * NV + v] = s;
    }
}

// ---------------------------------------------------------------------------
// MFMA distance GEMM over COMPACTED tokens (R21-proven BM=64 body).
// Block = 64 token slots x one g; 4 waves = 2 token-halves x 2 code-halves.
// Exact top-3 (ids for top-2); FULLBIT iff d3-d1<MARGIN3; flag iff
// d2-d1<MARGIN. Tail: fused gather + exact loss, scattered via tokL.
// ---------------------------------------------------------------------------
__global__ __launch_bounds__(256, 4) void mfma_gemm(
    const float* __restrict__ x, const f16* __restrict__ cbh,
    const float* __restrict__ cb, const float* __restrict__ c2b,
    const int* __restrict__ ncnt, const int* __restrict__ tokmap,
    float* __restrict__ out_ids, float* __restrict__ out_q,
    float* __restrict__ lossg, int* __restrict__ cnt,
    int* __restrict__ flags, int* __restrict__ cand2) {
    __shared__ __align__(16) f16 Bh[2][BN * ND];   // 2 x 16 KB
    __shared__ __align__(16) float c2s[NV];        // 4 KB
    __shared__ int idsL[BM];
    __shared__ int tokL[BM];

    const int tid = threadIdx.x;
    const int b = blockIdx.x;
    const int g = b & 7;
    const int count = *ncnt;
    const int tile_base = (b >> 3) * BM;
    if (tile_base >= count) return;
    const int lane = tid & 63;
    const int w = tid >> 6;
    const int wr = w & 1, wc = w >> 1;
    const int l15 = lane & 15, l4 = lane >> 4;

    // prologue: c2 -> LDS, issue tile-0 DMA, A load/convert under it
    ((float4*)c2s)[tid] = ((const float4*)(c2b + (size_t)g * NV))[tid];
    {
        const f16* sh = cbh + ((size_t)(g * 16 + 0)) * 8192;
#pragma unroll
        for (int it = 0; it < 4; ++it)
            gll16(sh + it * 2048 + tid * 8, &Bh[0][it * 2048 + tid * 8]);
    }

    int tokA_[2];
#pragma unroll
    for (int ti = 0; ti < 2; ++ti) {
        int slot = tile_base + wr * 32 + ti * 16 + l15;
        tokA_[ti] = tokmap[(slot < count) ? slot : 0];
    }

    half8 ah[4][2];   // [kk][ti]
#pragma unroll
    for (int kk = 0; kk < 4; ++kk)
#pragma unroll
        for (int ti = 0; ti < 2; ++ti) {
            const float* ap = x + ((size_t)tokA_[ti] * NG + g) * ND
                              + kk * 32 + l4 * 8;
            float4 p0 = *(const float4*)ap, p1 = *(const float4*)(ap + 4);
            float vv[8] = {p0.x, p0.y, p0.z, p0.w, p1.x, p1.y, p1.z, p1.w};
            half8 h;
#pragma unroll
            for (int j = 0; j < 8; ++j) h[j] = (f16)vv[j];
            ah[kk][ti] = h;
        }

    float d1s[2][4], d2s[2][4], d3s[2][4];
    int id1s[2][4], id2s[2][4];
#pragma unroll
    for (int ti = 0; ti < 2; ++ti)
#pragma unroll
        for (int r = 0; r < 4; ++r) {
            d1s[ti][r] = INFINITY;
            d2s[ti][r] = INFINITY;
            d3s[ti][r] = INFINITY;
            id1s[ti][r] = 0;
            id2s[ti][r] = 0;
        }

    int buf = 0;
#pragma unroll 1
    for (int t = 0; t < NT; ++t) {
        asm volatile("s_waitcnt vmcnt(0) lgkmcnt(0)" ::: "memory");
        __builtin_amdgcn_s_barrier();
        __builtin_amdgcn_sched_barrier(0);

        if (t + 1 < NT) {
            const f16* sh = cbh + ((size_t)(g * 16 + t + 1)) * 8192;
#pragma unroll
            for (int it = 0; it < 4; ++it)
                gll16(sh + it * 2048 + tid * 8,
                      &Bh[buf ^ 1][it * 2048 + tid * 8]);
        }

        f32x4 acc[2][2];
#pragma unroll
        for (int ti = 0; ti < 2; ++ti)
#pragma unroll
            for (int tj = 0; tj < 2; ++tj)
                acc[ti][tj] = (f32x4){0.f, 0.f, 0.f, 0.f};

#pragma unroll
        for (int kk = 0; kk < 4; ++kk) {
            half8 bh[2];
#pragma unroll
            for (int tj = 0; tj < 2; ++tj) {
                int rw = wc * 32 + tj * 16 + l15;
                bh[tj] = *(const half8*)(
                    &Bh[buf][rw * 128 + (((kk * 4 + l4) ^ (rw & 7)) << 3)]);
            }
#pragma unroll
            for (int ti = 0; ti < 2; ++ti)
#pragma unroll
                for (int tj = 0; tj < 2; ++tj)
                    acc[ti][tj] = __builtin_amdgcn_mfma_f32_16x16x32_f16(
                        ah[kk][ti], bh[tj], acc[ti][tj], 0, 0, 0);
        }

        // epilogue: exact sorted top-3 (ids for top-2)
#pragma unroll
        for (int tj = 0; tj < 2; ++tj) {
            int code = t * BN + wc * 32 + tj * 16 + l15;
            float c2v = c2s[code];
#pragma unroll
            for (int ti = 0; ti < 2; ++ti)
#pragma unroll
                for (int r = 0; r < 4; ++r) {
                    float dv = fmaf(-2.0f, acc[ti][tj][r], c2v);
                    bool lt1 = dv < d1s[ti][r];
                    bool lt2 = dv < d2s[ti][r];
                    bool lt3 = dv < d3s[ti][r];
                    d3s[ti][r] = lt2 ? d2s[ti][r] : (lt3 ? dv : d3s[ti][r]);
                    d2s[ti][r] = lt1 ? d1s[ti][r] : (lt2 ? dv : d2s[ti][r]);
                    id2s[ti][r] = lt1 ? id1s[ti][r] : (lt2 ? code : id2s[ti][r]);
                    d1s[ti][r] = lt1 ? dv : d1s[ti][r];
                    id1s[ti][r] = lt1 ? code : id1s[ti][r];
                }
        }
        buf ^= 1;
    }

    // merge: butterfly over l15 (sorted triples), then across wc via LDS
    __syncthreads();
    float4* red = (float4*)&Bh[0][0];            // 128 x float4
    float* redd3 = (float*)(red + 128);          // 128 x float
#pragma unroll
    for (int ti = 0; ti < 2; ++ti)
#pragma unroll
        for (int r = 0; r < 4; ++r) {
            float d1 = d1s[ti][r], d2 = d2s[ti][r], d3 = d3s[ti][r];
            int i1 = id1s[ti][r], i2 = id2s[ti][r];
#pragma unroll
            for (int m = 1; m < 16; m <<= 1) {
                float od1 = __shfl_xor(d1, m);
                float od2 = __shfl_xor(d2, m);
                float od3 = __shfl_xor(d3, m);
                int oi1 = __shfl_xor(i1, m);
                int oi2 = __shfl_xor(i2, m);
                bool ow = od1 < d1;
                float w1 = ow ? od1 : d1, w2 = ow ? od2 : d2, w3 = ow ? od3 : d3;
                int wi1 = ow ? oi1 : i1, wi2 = ow ? oi2 : i2;
                float l1 = ow ? d1 : od1, l2 = ow ? d2 : od2;
                int li1 = ow ? i1 : oi1;
                d1 = w1; i1 = wi1;
                bool t2 = w2 < l1;
                d2 = t2 ? w2 : l1;
                i2 = t2 ? wi2 : li1;
                d3 = t2 ? fminf(w3, l1) : fminf(w2, l2);
            }
            if (l15 == 0) {
                int o = wc * BM + wr * 32 + ti * 16 + l4 * 4 + r;
                red[o] = make_float4(d1, __int_as_float(i1), d2,
                                     __int_as_float(i2));
                redd3[o] = d3;
            }
        }
    __syncthreads();

    if (tid < BM) {
        float4 A = red[tid], C = red[BM + tid];
        float a3 = redd3[tid], c3 = redd3[BM + tid];
        float a1 = A.x, a2 = A.z, c1 = C.x, c2q = C.z;
        int ai1 = __float_as_int(A.y), ai2 = __float_as_int(A.w);
        int ci1 = __float_as_int(C.y), ci2 = __float_as_int(C.w);
        bool cw = c1 < a1;
        float w1 = cw ? c1 : a1, w2 = cw ? c2q : a2, w3 = cw ? c3 : a3;
        int wi1 = cw ? ci1 : ai1, wi2 = cw ? ci2 : ai2;
        float l1 = cw ? a1 : c1, l2 = cw ? a2 : c2q;
        int li1 = cw ? ai1 : ci1;
        float d1 = w1;
        int i1 = wi1;
        bool t2 = w2 < l1;
        float d2 = t2 ? w2 : l1;
        int i2 = t2 ? wi2 : li1;
        float d3 = t2 ? fminf(w3, l1) : fminf(w2, l2);

        int slot = tile_base + tid;
        if (slot < count) {
            int tok = tokmap[slot];
            int idx = tok * NG + g;
            out_ids[idx] = (float)i1;
            idsL[tid] = i1;
            tokL[tid] = tok;
            if (d2 - d1 < MARGIN) {
                int pos = atomicAdd(cnt, 1);
                flags[pos] = idx;
                cand2[idx] = i2 | ((d3 - d1 < MARGIN3) ? (int)FULLBIT : 0);
            }
        } else {
            idsL[tid] = -1;
        }
    }
    __syncthreads();

    // fused gather + EXACT loss (scattered by tokL; garbage slots skipped)
#pragma unroll
    for (int it = 0; it < 8; ++it) {
        int i = it * 256 + tid;
        int tl = i >> 5, d4 = i & 31;
        int id = idsL[tl];
        if (id >= 0) {
            int tok = tokL[tl];
            size_t rowo = ((size_t)tok * NG + g) * ND;
            float4 q = ((const float4*)(cb + ((size_t)id * NG + g) * ND))[d4];
            float4 a = ((const float4*)(x + rowo))[d4];
            float e0 = q.x - a.x, e1 = q.y - a.y;
            float e2 = q.z - a.z, e3 = q.w - a.w;
            float s = e0 * e0 + e1 * e1 + e2 * e2 + e3 * e3;
            ((float4*)(out_q + rowo))[d4] = q;
#pragma unroll
            for (int m = 1; m < 32; m <<= 1) s += __shfl_xor(s, m);
            if (d4 == 0) lossg[tok * NG + g] = s;
        }
    }
}

// ---------------------------------------------------------------------------
// recheck: pass 1 wave-per-flag 2-candidate compare; pass 2 full scan.
// ---------------------------------------------------------------------------
__global__ __launch_bounds__(256) void recheck(
    const float* __restrict__ x, const float* __restrict__ cb,
    const float* __restrict__ c2w, const int* __restrict__ cnt,
    const int* __restrict__ flags, const int* __restrict__ cand2,
    float* __restrict__ out_ids, float* __restrict__ out_q,
    float* __restrict__ lossg) {
    __shared__ __align__(16) float xs[ND];
    __shared__ float2 redw[4];
    __shared__ int bidS;
    const int tid = threadIdx.x;
    const int lane = tid & 63;
    const int w = tid >> 6;
    const int n_f = cnt[0];

    for (int f = blockIdx.x * 4 + w; f < n_f; f += gridDim.x * 4) {
        int idx = flags[f];
        unsigned cc = (unsigned)cand2[idx];
        if (cc & FULLBIT) continue;
        int g = idx & 7;
        int id1 = (int)out_ids[idx];
        int id2 = (int)(cc & ~FULLBIT);
        float2 xv = ((const float2*)(x + (size_t)idx * ND))[lane];
        float2 av = ((const float2*)(cb + ((size_t)id1 * NG + g) * ND))[lane];
        float2 bv = ((const float2*)(cb + ((size_t)id2 * NG + g) * ND))[lane];
        float eA0 = xv.x - av.x, eA1 = xv.y - av.y;
        float eB0 = xv.x - bv.x, eB1 = xv.y - bv.y;
        float sA = eA0 * eA0 + eA1 * eA1;
        float sB = eB0 * eB0 + eB1 * eB1;
#pragma unroll
        for (int m = 1; m < 64; m <<= 1) {
            sA += __shfl_xor(sA, m);
            sB += __shfl_xor(sB, m);
        }
        int win;
        float sw;
        if (sA < sB) { win = id1; sw = sA; }
        else if (sB < sA) { win = id2; sw = sB; }
        else { win = (id1 < id2) ? id1 : id2; sw = sA; }
        if (win != id1) {
            if (lane == 0) {
                out_ids[idx] = (float)win;
                lossg[idx] = sw;
            }
            if (lane < 32) {
                float4 q = ((const float4*)(cb + ((size_t)win * NG + g) * ND))[lane];
                ((float4*)(out_q + (size_t)idx * ND))[lane] = q;
            }
        }
    }
    __syncthreads();

    for (int f = blockIdx.x; f < n_f; f += gridDim.x) {
        int idx = flags[f];
        if (!(((unsigned)cand2[idx]) & FULLBIT)) continue;
        int g = idx & 7;
        __syncthreads();
        if (tid < 32)
            ((float4*)xs)[tid] = ((const float4*)(x + (size_t)idx * ND))[tid];
        __syncthreads();

        float rr[8];
#pragma unroll
        for (int j = 0; j < 8; ++j) rr[j] = 0.0f;
#pragma unroll
        for (int i = 0; i < 32; ++i) {
            float4 v = ((const float4*)xs)[i];
            int j0 = (i * 4) & 7;
            rr[j0 + 0] = __fadd_rn(rr[j0 + 0], __fmul_rn(v.x, v.x));
            rr[j0 + 1] = __fadd_rn(rr[j0 + 1], __fmul_rn(v.y, v.y));
            rr[j0 + 2] = __fadd_rn(rr[j0 + 2], __fmul_rn(v.z, v.z));
            rr[j0 + 3] = __fadd_rn(rr[j0 + 3], __fmul_rn(v.w, v.w));
        }
        float x2v = __fadd_rn(
            __fadd_rn(__fadd_rn(rr[0], rr[1]), __fadd_rn(rr[2], rr[3])),
            __fadd_rn(__fadd_rn(rr[4], rr[5]), __fadd_rn(rr[6], rr[7])));

        float best = INFINITY;
        int bid = 0x7FFFFFFF;
        float s0 = 0.f, s1 = 0.f, s2 = 0.f, s3 = 0.f;
#pragma unroll
        for (int i = 0; i < 32; ++i) {
            float4 a = ((const float4*)xs)[i];
            float4 q0 = ((const float4*)(cb + ((size_t)(tid) * NG + g) * ND))[i];
            float4 q1 = ((const float4*)(cb + ((size_t)(tid + 256) * NG + g) * ND))[i];
            float4 q2 = ((const float4*)(cb + ((size_t)(tid + 512) * NG + g) * ND))[i];
            float4 q3 = ((const float4*)(cb + ((size_t)(tid + 768) * NG + g) * ND))[i];
            s0 = fmaf(a.x, q0.x, s0); s0 = fmaf(a.y, q0.y, s0);
            s0 = fmaf(a.z, q0.z, s0); s0 = fmaf(a.w, q0.w, s0);
            s1 = fmaf(a.x, q1.x, s1); s1 = fmaf(a.y, q1.y, s1);
            s1 = fmaf(a.z, q1.z, s1); s1 = fmaf(a.w, q1.w, s1);
            s2 = fmaf(a.x, q2.x, s2); s2 = fmaf(a.y, q2.y, s2);
            s2 = fmaf(a.z, q2.z, s2); s2 = fmaf(a.w, q2.w, s2);
            s3 = fmaf(a.x, q3.x, s3); s3 = fmaf(a.y, q3.y, s3);
            s3 = fmaf(a.z, q3.z, s3); s3 = fmaf(a.w, q3.w, s3);
        }
        float dd[4] = {s0, s1, s2, s3};
#pragma unroll
        for (int jj = 0; jj < 4; ++jj) {
            int c = tid + 256 * jj;
            float d = __fadd_rn(__fsub_rn(x2v, __fmul_rn(2.0f, dd[jj])),
                                c2w[(size_t)c * NG + g]);
            if (d < best || (d == best && c < bid)) { best = d; bid = c; }
        }
#pragma unroll
        for (int m = 1; m < 64; m <<= 1) {
            float od = __shfl_xor(best, m);
            int ob = __shfl_xor(bid, m);
            if (od < best || (od == best && ob < bid)) { best = od; bid = ob; }
        }
        if (lane == 0) redw[w] = make_float2(best, __int_as_float(bid));
        __syncthreads();
        if (tid == 0) {
            float b2 = redw[0].x;
            int i2 = __float_as_int(redw[0].y);
#pragma unroll
            for (int ww = 1; ww < 4; ++ww) {
                float ob = redw[ww].x;
                int oi = __float_as_int(redw[ww].y);
                if (ob < b2 || (ob == b2 && oi < i2)) { b2 = ob; i2 = oi; }
            }
            out_ids[idx] = (float)i2;
            bidS = i2;
        }
        __syncthreads();
        if (tid < 32) {
            float4 q = ((const float4*)(cb + ((size_t)bidS * NG + g) * ND))[tid];
            ((float4*)(out_q + (size_t)idx * ND))[tid] = q;
            float4 a = ((const float4*)xs)[tid];
            float e0 = q.x - a.x, e1 = q.y - a.y;
            float e2 = q.z - a.z, e3 = q.w - a.w;
            float s = e0 * e0 + e1 * e1 + e2 * e2 + e3 * e3;
#pragma unroll
            for (int m = 1; m < 32; m <<= 1) s += __shfl_xor(s, m);
            if (tid == 0) lossg[idx] = s;
        }
    }
}

// ---------------------------------------------------------------------------
__global__ __launch_bounds__(256) void loss_part(
    const float* __restrict__ lossg, float* __restrict__ part) {
    __shared__ float sr[256];
    const int tid = threadIdx.x;
    float4 v = ((const float4*)lossg)[blockIdx.x * 256 + tid];
    sr[tid] = ((v.x + v.y) + (v.z + v.w));
    __syncthreads();
    for (int st = 128; st > 0; st >>= 1) {
        if (tid < st) sr[tid] += sr[tid + st];
        __syncthreads();
    }
    if (tid == 0) part[blockIdx.x] = sr[0];
}

// ---------------------------------------------------------------------------
// final: msum = cnt[1] (token count from compaction); 64-lane tree sum.
// ---------------------------------------------------------------------------
__global__ __launch_bounds__(64) void final_kernel(
    const int* __restrict__ cnt, const float* __restrict__ part,
    float* __restrict__ out_l) {
    const int tid = threadIdx.x;
    float s = part[tid];
#pragma unroll
    for (int m = 1; m < 64; m <<= 1) s += __shfl_xor(s, m);
    if (tid == 0) {
        float k = s / (float)cnt[1];
        out_l[0] = k;
        out_l[1] = k;
        out_l[2] = k + k;
    }
}

// ---------------------------------------------------------------------------
extern "C" void kernel_launch(void* const* d_in, const int* in_sizes, int n_in,
                              void* d_out, int out_size, void* d_ws, size_t ws_size,
                              hipStream_t stream) {
    const float* x = (const float*)d_in[0];
    const int* pad = (const int*)d_in[1];
    const float* cb = (const float*)d_in[2];
    float* out = (float*)d_out;
    float* ws = (float*)d_ws;

    float* ws_c2a = ws + OFF_C2A;
    float* ws_c2b = ws + OFF_C2B;
    float* ws_lossg = ws + OFF_LOSSG;
    int* ws_cnt = (int*)(ws + OFF_CNT);      // [0]=flag cnt, [1]=token cnt
    int* ws_flags = (int*)(ws + OFF_FLAGS);
    f16* cbh = (f16*)(ws + OFF_CBH);
    float* ws_part = ws + OFF_PART;
    int* ws_cand2 = (int*)(ws + OFF_CAND2);
    int* ws_tokmap = (int*)(ws + OFF_TOKMAP);

    prep_kernel<<<1025, 256, 0, stream>>>(cb, pad, cbh, ws_c2a, ws_c2b,
                                          ws_cnt, ws_tokmap, out + OUT_IDS,
                                          out + OUT_Q, ws_lossg);
    mfma_gemm<<<(BT / BM) * NG, 256, 0, stream>>>(x, cbh, cb, ws_c2b,
                                                  ws_cnt + 1, ws_tokmap,
                                                  out + OUT_IDS, out + OUT_Q,
                                                  ws_lossg, ws_cnt, ws_flags,
                                                  ws_cand2);
    recheck<<<512, 256, 0, stream>>>(x, cb, ws_c2a, ws_cnt, ws_flags,
                                     ws_cand2, out + OUT_IDS, out + OUT_Q,
                                     ws_lossg);
    loss_part<<<64, 256, 0, stream>>>(ws_lossg, ws_part);
    final_kernel<<<1, 64, 0, stream>>>(ws_cnt, ws_part, out + OUT_L);
}

// Round 24
// 73.495 us; speedup vs baseline: 1.3717x; 1.0065x over previous
//
#include <hip/hip_runtime.h>
#include <math.h>

typedef _Float16 f16;
typedef f16 half8 __attribute__((ext_vector_type(8)));
typedef float f32x4 __attribute__((ext_vector_type(4)));

// Problem sizes: B=4, T=2048, G=8, D=128, V=1024
#define BT 8192
#define NG 8
#define ND 128
#define NV 1024
#define MARGIN  0.08f    // flag threshold (d2-d1)
#define MARGIN3 0.16f    // FULLBIT threshold (d3-d1)
#define BM 64            // token slots per block (R19/R21-proven)
#define BN 64            // codes per tile
#define NT 16            // code tiles
#define FULLBIT 0x40000000u

// d_out layout (float32): ids[65536] | quantized_st[8388608] | 3 losses
#define OUT_IDS 0
#define OUT_Q   65536
#define OUT_L   (65536 + 8388608)

// ws float offsets (~3.4 MB)
#define OFF_C2A    0                   // c2 [v*8+g] (recheck)          (8192)
#define OFF_C2B    8192                // c2 [g*NV+v] (gemm)            (8192)
#define OFF_LOSSG  81920               // per-(token,g) loss partial    (65536)
#define OFF_CNT    147456              // [0]=flag count, [1]=tok count (8)
#define OFF_FLAGS  147464              // flag list                     (65536)
#define OFF_CBH    213000              // cbh fp16 swizzled stream      (524288)
#define OFF_PART   (OFF_CBH + 524288)  // loss partials                 (64)
#define OFF_CAND2  (OFF_PART + 64)     // id2 | FULLBIT per flagged idx (65536)
#define OFF_TOKMAP (OFF_CAND2 + 65536) // compacted non-pad tokens      (8192)

// ---------------------------------------------------------------------------
__device__ __forceinline__ void gll16(const f16* g, f16* l) {
    __builtin_amdgcn_global_load_lds(
        (const __attribute__((address_space(1))) unsigned int*)g,
        (__attribute__((address_space(3))) unsigned int*)l, 16, 0, 0);
}

// ---------------------------------------------------------------------------
// prep (fused, 1025 blocks):
//   blocks 0-511 : c2 both layouts (R1-exact) + pre-swizzled fp16 cb stream
//   block  512   : deterministic token compaction (prefix sum, sorted
//                  tokmap); writes cnt[1]=token count, cnt[0]=0
//   blocks 513+  : padfill (padded tokens: q=0, ids=-1, loss=0)
// ---------------------------------------------------------------------------
__global__ __launch_bounds__(256) void prep_kernel(
    const float* __restrict__ cb, const int* __restrict__ pad,
    f16* __restrict__ cbh, float* __restrict__ c2a, float* __restrict__ c2b,
    int* __restrict__ cnt, int* __restrict__ tokmap,
    float* __restrict__ out_ids, float* __restrict__ out_q,
    float* __restrict__ lossg) {
    const int tid = threadIdx.x;

    if (blockIdx.x == 512) {              // compaction block
        __shared__ int ps[256];
        const int base = tid * 32;
        int c = 0;
#pragma unroll
        for (int i = 0; i < 32; ++i) c += 1 - pad[base + i];
        ps[tid] = c;
        __syncthreads();
        for (int st = 1; st < 256; st <<= 1) {
            int v = (tid >= st) ? ps[tid - st] : 0;
            __syncthreads();
            ps[tid] += v;
            __syncthreads();
        }
        int o = ps[tid] - c;
        if (tid == 255) {
            cnt[1] = ps[255];
            cnt[0] = 0;
        }
        for (int i = 0; i < 32; ++i) {
            int tok = base + i;
            if (!pad[tok]) tokmap[o++] = tok;
        }
        return;
    }

    if (blockIdx.x > 512) {               // padfill blocks (512 of them)
        const int gt = (blockIdx.x - 513) * 256 + tid;   // 131072 threads
        const float4 z = make_float4(0.f, 0.f, 0.f, 0.f);
#pragma unroll 4
        for (int i = gt; i < BT * NG * ND / 4; i += 512 * 256) {
            int tok = i >> 8;             // 256 float4 per token
            if (pad[tok]) ((float4*)out_q)[i] = z;
        }
        if (gt < BT * NG) {
            int tok = gt >> 3;
            if (pad[tok]) {
                out_ids[gt] = -1.0f;
                lossg[gt] = 0.0f;
            }
        }
        return;
    }

    __shared__ float prod[16][16][9];
    __shared__ float rbuf[16][8];
    const int rloc = tid >> 4, t = tid & 15;
    const int idx = blockIdx.x * 16 + rloc;   // cb row = v*8+g
    const int v = idx >> 3, g = idx & 7;
    const int rl = v & 63;
    const float4* row4 = (const float4*)(cb + (size_t)idx * ND);

    float4 a = row4[t * 2], b = row4[t * 2 + 1];
    float vv[8] = {a.x, a.y, a.z, a.w, b.x, b.y, b.z, b.w};
    half8 h;
#pragma unroll
    for (int e = 0; e < 8; ++e) {
        prod[rloc][t][e] = __fmul_rn(vv[e], vv[e]);
        h[e] = (f16)vv[e];
    }
    int cn = v >> 6;
    size_t base = ((size_t)(g * 16 + cn)) * 8192 + rl * 128;
    *(half8*)(cbh + base + ((t ^ (rl & 7)) * 8)) = h;
    __syncthreads();

    if (t < 8) {
        float r = 0.f;
#pragma unroll
        for (int tt = 0; tt < 16; ++tt)
            r = __fadd_rn(r, prod[rloc][tt][t]);
        rbuf[rloc][t] = r;
    }
    __syncthreads();
    if (t == 0) {
        float s = __fadd_rn(
            __fadd_rn(__fadd_rn(rbuf[rloc][0], rbuf[rloc][1]),
                      __fadd_rn(rbuf[rloc][2], rbuf[rloc][3])),
            __fadd_rn(__fadd_rn(rbuf[rloc][4], rbuf[rloc][5]),
                      __fadd_rn(rbuf[rloc][6], rbuf[rloc][7])));
        c2a[idx] = s;
        c2b[g * NV + v] = s;
    }
}

// ---------------------------------------------------------------------------
// MFMA distance GEMM over COMPACTED tokens, TRIPLE-buffered depth-2 DMA.
// Per-tile: wait vmcnt(8) [drains tile t; tile t+1 stays IN FLIGHT, having
// had 2 tile-periods]; barrier; issue tile t+2 into buf (t+2)%3 (== buf
// (t-1)%3, readers all passed the barrier); compute tile t.
// All arithmetic / epilogue / merge byte-identical to R23 -> bitwise ids.
// ---------------------------------------------------------------------------
__global__ __launch_bounds__(256, 2) void mfma_gemm(
    const float* __restrict__ x, const f16* __restrict__ cbh,
    const float* __restrict__ cb, const float* __restrict__ c2b,
    const int* __restrict__ ncnt, const int* __restrict__ tokmap,
    float* __restrict__ out_ids, float* __restrict__ out_q,
    float* __restrict__ lossg, int* __restrict__ cnt,
    int* __restrict__ flags, int* __restrict__ cand2) {
    __shared__ __align__(16) f16 Bh[3][BN * ND];   // 3 x 16 KB
    __shared__ __align__(16) float c2s[NV];        // 4 KB
    __shared__ int idsL[BM];
    __shared__ int tokL[BM];

    const int tid = threadIdx.x;
    const int b = blockIdx.x;
    const int g = b & 7;
    const int count = *ncnt;
    const int tile_base = (b >> 3) * BM;
    if (tile_base >= count) return;
    const int lane = tid & 63;
    const int w = tid >> 6;
    const int wr = w & 1, wc = w >> 1;
    const int l15 = lane & 15, l4 = lane >> 4;

    // prologue: c2 -> LDS, issue tiles 0 AND 1, A load/convert under them
    ((float4*)c2s)[tid] = ((const float4*)(c2b + (size_t)g * NV))[tid];
    {
        const f16* sh0 = cbh + ((size_t)(g * 16 + 0)) * 8192;
#pragma unroll
        for (int it = 0; it < 4; ++it)
            gll16(sh0 + it * 2048 + tid * 8, &Bh[0][it * 2048 + tid * 8]);
        const f16* sh1 = cbh + ((size_t)(g * 16 + 1)) * 8192;
#pragma unroll
        for (int it = 0; it < 4; ++it)
            gll16(sh1 + it * 2048 + tid * 8, &Bh[1][it * 2048 + tid * 8]);
    }

    int tokA_[2];
#pragma unroll
    for (int ti = 0; ti < 2; ++ti) {
        int slot = tile_base + wr * 32 + ti * 16 + l15;
        tokA_[ti] = tokmap[(slot < count) ? slot : 0];
    }

    half8 ah[4][2];   // [kk][ti]
#pragma unroll
    for (int kk = 0; kk < 4; ++kk)
#pragma unroll
        for (int ti = 0; ti < 2; ++ti) {
            const float* ap = x + ((size_t)tokA_[ti] * NG + g) * ND
                              + kk * 32 + l4 * 8;
            float4 p0 = *(const float4*)ap, p1 = *(const float4*)(ap + 4);
            float vv[8] = {p0.x, p0.y, p0.z, p0.w, p1.x, p1.y, p1.z, p1.w};
            half8 h;
#pragma unroll
            for (int j = 0; j < 8; ++j) h[j] = (f16)vv[j];
            ah[kk][ti] = h;
        }

    float d1s[2][4], d2s[2][4], d3s[2][4];
    int id1s[2][4], id2s[2][4];
#pragma unroll
    for (int ti = 0; ti < 2; ++ti)
#pragma unroll
        for (int r = 0; r < 4; ++r) {
            d1s[ti][r] = INFINITY;
            d2s[ti][r] = INFINITY;
            d3s[ti][r] = INFINITY;
            id1s[ti][r] = 0;
            id2s[ti][r] = 0;
        }

    int buf = 0;   // tile t lives in buffer t % 3
#pragma unroll 1
    for (int t = 0; t < NT; ++t) {
        // drain tile t's 8 loads; tile t+1's 8 stay in flight (depth-2)
        if (t < NT - 1)
            asm volatile("s_waitcnt vmcnt(8) lgkmcnt(0)" ::: "memory");
        else
            asm volatile("s_waitcnt vmcnt(0) lgkmcnt(0)" ::: "memory");
        __builtin_amdgcn_s_barrier();
        __builtin_amdgcn_sched_barrier(0);

        // issue tile t+2 into buffer (t+2)%3 (readers passed the barrier)
        if (t + 2 < NT) {
            int nb = buf + 2;
            nb = (nb >= 3) ? nb - 3 : nb;
            const f16* sh = cbh + ((size_t)(g * 16 + t + 2)) * 8192;
#pragma unroll
            for (int it = 0; it < 4; ++it)
                gll16(sh + it * 2048 + tid * 8,
                      &Bh[nb][it * 2048 + tid * 8]);
        }

        f32x4 acc[2][2];
#pragma unroll
        for (int ti = 0; ti < 2; ++ti)
#pragma unroll
            for (int tj = 0; tj < 2; ++tj)
                acc[ti][tj] = (f32x4){0.f, 0.f, 0.f, 0.f};

#pragma unroll
        for (int kk = 0; kk < 4; ++kk) {
            half8 bh[2];
#pragma unroll
            for (int tj = 0; tj < 2; ++tj) {
                int rw = wc * 32 + tj * 16 + l15;
                bh[tj] = *(const half8*)(
                    &Bh[buf][rw * 128 + (((kk * 4 + l4) ^ (rw & 7)) << 3)]);
            }
#pragma unroll
            for (int ti = 0; ti < 2; ++ti)
#pragma unroll
                for (int tj = 0; tj < 2; ++tj)
                    acc[ti][tj] = __builtin_amdgcn_mfma_f32_16x16x32_f16(
                        ah[kk][ti], bh[tj], acc[ti][tj], 0, 0, 0);
        }

        // epilogue: exact sorted top-3 (ids for top-2)
#pragma unroll
        for (int tj = 0; tj < 2; ++tj) {
            int code = t * BN + wc * 32 + tj * 16 + l15;
            float c2v = c2s[code];
#pragma unroll
            for (int ti = 0; ti < 2; ++ti)
#pragma unroll
                for (int r = 0; r < 4; ++r) {
                    float dv = fmaf(-2.0f, acc[ti][tj][r], c2v);
                    bool lt1 = dv < d1s[ti][r];
                    bool lt2 = dv < d2s[ti][r];
                    bool lt3 = dv < d3s[ti][r];
                    d3s[ti][r] = lt2 ? d2s[ti][r] : (lt3 ? dv : d3s[ti][r]);
                    d2s[ti][r] = lt1 ? d1s[ti][r] : (lt2 ? dv : d2s[ti][r]);
                    id2s[ti][r] = lt1 ? id1s[ti][r] : (lt2 ? code : id2s[ti][r]);
                    d1s[ti][r] = lt1 ? dv : d1s[ti][r];
                    id1s[ti][r] = lt1 ? code : id1s[ti][r];
                }
        }
        buf = (buf == 2) ? 0 : buf + 1;
    }

    // merge: butterfly over l15 (sorted triples), then across wc via LDS
    __syncthreads();
    float4* red = (float4*)&Bh[0][0];            // 128 x float4
    float* redd3 = (float*)(red + 128);          // 128 x float
#pragma unroll
    for (int ti = 0; ti < 2; ++ti)
#pragma unroll
        for (int r = 0; r < 4; ++r) {
            float d1 = d1s[ti][r], d2 = d2s[ti][r], d3 = d3s[ti][r];
            int i1 = id1s[ti][r], i2 = id2s[ti][r];
#pragma unroll
            for (int m = 1; m < 16; m <<= 1) {
                float od1 = __shfl_xor(d1, m);
                float od2 = __shfl_xor(d2, m);
                float od3 = __shfl_xor(d3, m);
                int oi1 = __shfl_xor(i1, m);
                int oi2 = __shfl_xor(i2, m);
                bool ow = od1 < d1;
                float w1 = ow ? od1 : d1, w2 = ow ? od2 : d2, w3 = ow ? od3 : d3;
                int wi1 = ow ? oi1 : i1, wi2 = ow ? oi2 : i2;
                float l1 = ow ? d1 : od1, l2 = ow ? d2 : od2;
                int li1 = ow ? i1 : oi1;
                d1 = w1; i1 = wi1;
                bool t2 = w2 < l1;
                d2 = t2 ? w2 : l1;
                i2 = t2 ? wi2 : li1;
                d3 = t2 ? fminf(w3, l1) : fminf(w2, l2);
            }
            if (l15 == 0) {
                int o = wc * BM + wr * 32 + ti * 16 + l4 * 4 + r;
                red[o] = make_float4(d1, __int_as_float(i1), d2,
                                     __int_as_float(i2));
                redd3[o] = d3;
            }
        }
    __syncthreads();

    if (tid < BM) {
        float4 A = red[tid], C = red[BM + tid];
        float a3 = redd3[tid], c3 = redd3[BM + tid];
        float a1 = A.x, a2 = A.z, c1 = C.x, c2q = C.z;
        int ai1 = __float_as_int(A.y), ai2 = __float_as_int(A.w);
        int ci1 = __float_as_int(C.y), ci2 = __float_as_int(C.w);
        bool cw = c1 < a1;
        float w1 = cw ? c1 : a1, w2 = cw ? c2q : a2, w3 = cw ? c3 : a3;
        int wi1 = cw ? ci1 : ai1, wi2 = cw ? ci2 : ai2;
        float l1 = cw ? a1 : c1, l2 = cw ? a2 : c2q;
        int li1 = cw ? ai1 : ci1;
        float d1 = w1;
        int i1 = wi1;
        bool t2 = w2 < l1;
        float d2 = t2 ? w2 : l1;
        int i2 = t2 ? wi2 : li1;
        float d3 = t2 ? fminf(w3, l1) : fminf(w2, l2);

        int slot = tile_base + tid;
        if (slot < count) {
            int tok = tokmap[slot];
            int idx = tok * NG + g;
            out_ids[idx] = (float)i1;
            idsL[tid] = i1;
            tokL[tid] = tok;
            if (d2 - d1 < MARGIN) {
                int pos = atomicAdd(cnt, 1);
                flags[pos] = idx;
                cand2[idx] = i2 | ((d3 - d1 < MARGIN3) ? (int)FULLBIT : 0);
            }
        } else {
            idsL[tid] = -1;
        }
    }
    __syncthreads();

    // fused gather + EXACT loss (scattered by tokL; garbage slots skipped)
#pragma unroll
    for (int it = 0; it < 8; ++it) {
        int i = it * 256 + tid;
        int tl = i >> 5, d4 = i & 31;
        int id = idsL[tl];
        if (id >= 0) {
            int tok = tokL[tl];
            size_t rowo = ((size_t)tok * NG + g) * ND;
            float4 q = ((const float4*)(cb + ((size_t)id * NG + g) * ND))[d4];
            float4 a = ((const float4*)(x + rowo))[d4];
            float e0 = q.x - a.x, e1 = q.y - a.y;
            float e2 = q.z - a.z, e3 = q.w - a.w;
            float s = e0 * e0 + e1 * e1 + e2 * e2 + e3 * e3;
            ((float4*)(out_q + rowo))[d4] = q;
#pragma unroll
            for (int m = 1; m < 32; m <<= 1) s += __shfl_xor(s, m);
            if (d4 == 0) lossg[tok * NG + g] = s;
        }
    }
}

// ---------------------------------------------------------------------------
// recheck: pass 1 wave-per-flag 2-candidate compare; pass 2 full scan.
// ---------------------------------------------------------------------------
__global__ __launch_bounds__(256) void recheck(
    const float* __restrict__ x, const float* __restrict__ cb,
    const float* __restrict__ c2w, const int* __restrict__ cnt,
    const int* __restrict__ flags, const int* __restrict__ cand2,
    float* __restrict__ out_ids, float* __restrict__ out_q,
    float* __restrict__ lossg) {
    __shared__ __align__(16) float xs[ND];
    __shared__ float2 redw[4];
    __shared__ int bidS;
    const int tid = threadIdx.x;
    const int lane = tid & 63;
    const int w = tid >> 6;
    const int n_f = cnt[0];

    for (int f = blockIdx.x * 4 + w; f < n_f; f += gridDim.x * 4) {
        int idx = flags[f];
        unsigned cc = (unsigned)cand2[idx];
        if (cc & FULLBIT) continue;
        int g = idx & 7;
        int id1 = (int)out_ids[idx];
        int id2 = (int)(cc & ~FULLBIT);
        float2 xv = ((const float2*)(x + (size_t)idx * ND))[lane];
        float2 av = ((const float2*)(cb + ((size_t)id1 * NG + g) * ND))[lane];
        float2 bv = ((const float2*)(cb + ((size_t)id2 * NG + g) * ND))[lane];
        float eA0 = xv.x - av.x, eA1 = xv.y - av.y;
        float eB0 = xv.x - bv.x, eB1 = xv.y - bv.y;
        float sA = eA0 * eA0 + eA1 * eA1;
        float sB = eB0 * eB0 + eB1 * eB1;
#pragma unroll
        for (int m = 1; m < 64; m <<= 1) {
            sA += __shfl_xor(sA, m);
            sB += __shfl_xor(sB, m);
        }
        int win;
        float sw;
        if (sA < sB) { win = id1; sw = sA; }
        else if (sB < sA) { win = id2; sw = sB; }
        else { win = (id1 < id2) ? id1 : id2; sw = sA; }
        if (win != id1) {
            if (lane == 0) {
                out_ids[idx] = (float)win;
                lossg[idx] = sw;
            }
            if (lane < 32) {
                float4 q = ((const float4*)(cb + ((size_t)win * NG + g) * ND))[lane];
                ((float4*)(out_q + (size_t)idx * ND))[lane] = q;
            }
        }
    }
    __syncthreads();

    for (int f = blockIdx.x; f < n_f; f += gridDim.x) {
        int idx = flags[f];
        if (!(((unsigned)cand2[idx]) & FULLBIT)) continue;
        int g = idx & 7;
        __syncthreads();
        if (tid < 32)
            ((float4*)xs)[tid] = ((const float4*)(x + (size_t)idx * ND))[tid];
        __syncthreads();

        float rr[8];
#pragma unroll
        for (int j = 0; j < 8; ++j) rr[j] = 0.0f;
#pragma unroll
        for (int i = 0; i < 32; ++i) {
            float4 v = ((const float4*)xs)[i];
            int j0 = (i * 4) & 7;
            rr[j0 + 0] = __fadd_rn(rr[j0 + 0], __fmul_rn(v.x, v.x));
            rr[j0 + 1] = __fadd_rn(rr[j0 + 1], __fmul_rn(v.y, v.y));
            rr[j0 + 2] = __fadd_rn(rr[j0 + 2], __fmul_rn(v.z, v.z));
            rr[j0 + 3] = __fadd_rn(rr[j0 + 3], __fmul_rn(v.w, v.w));
        }
        float x2v = __fadd_rn(
            __fadd_rn(__fadd_rn(rr[0], rr[1]), __fadd_rn(rr[2], rr[3])),
            __fadd_rn(__fadd_rn(rr[4], rr[5]), __fadd_rn(rr[6], rr[7])));

        float best = INFINITY;
        int bid = 0x7FFFFFFF;
        float s0 = 0.f, s1 = 0.f, s2 = 0.f, s3 = 0.f;
#pragma unroll
        for (int i = 0; i < 32; ++i) {
            float4 a = ((const float4*)xs)[i];
            float4 q0 = ((const float4*)(cb + ((size_t)(tid) * NG + g) * ND))[i];
            float4 q1 = ((const float4*)(cb + ((size_t)(tid + 256) * NG + g) * ND))[i];
            float4 q2 = ((const float4*)(cb + ((size_t)(tid + 512) * NG + g) * ND))[i];
            float4 q3 = ((const float4*)(cb + ((size_t)(tid + 768) * NG + g) * ND))[i];
            s0 = fmaf(a.x, q0.x, s0); s0 = fmaf(a.y, q0.y, s0);
            s0 = fmaf(a.z, q0.z, s0); s0 = fmaf(a.w, q0.w, s0);
            s1 = fmaf(a.x, q1.x, s1); s1 = fmaf(a.y, q1.y, s1);
            s1 = fmaf(a.z, q1.z, s1); s1 = fmaf(a.w, q1.w, s1);
            s2 = fmaf(a.x, q2.x, s2); s2 = fmaf(a.y, q2.y, s2);
            s2 = fmaf(a.z, q2.z, s2); s2 = fmaf(a.w, q2.w, s2);
            s3 = fmaf(a.x, q3.x, s3); s3 = fmaf(a.y, q3.y, s3);
            s3 = fmaf(a.z, q3.z, s3); s3 = fmaf(a.w, q3.w, s3);
        }
        float dd[4] = {s0, s1, s2, s3};
#pragma unroll
        for (int jj = 0; jj < 4; ++jj) {
            int c = tid + 256 * jj;
            float d = __fadd_rn(__fsub_rn(x2v, __fmul_rn(2.0f, dd[jj])),
                                c2w[(size_t)c * NG + g]);
            if (d < best || (d == best && c < bid)) { best = d; bid = c; }
        }
#pragma unroll
        for (int m = 1; m < 64; m <<= 1) {
            float od = __shfl_xor(best, m);
            int ob = __shfl_xor(bid, m);
            if (od < best || (od == best && ob < bid)) { best = od; bid = ob; }
        }
        if (lane == 0) redw[w] = make_float2(best, __int_as_float(bid));
        __syncthreads();
        if (tid == 0) {
            float b2 = redw[0].x;
            int i2 = __float_as_int(redw[0].y);
#pragma unroll
            for (int ww = 1; ww < 4; ++ww) {
                float ob = redw[ww].x;
                int oi = __float_as_int(redw[ww].y);
                if (ob < b2 || (ob == b2 && oi < i2)) { b2 = ob; i2 = oi; }
            }
            out_ids[idx] = (float)i2;
            bidS = i2;
        }
        __syncthreads();
        if (tid < 32) {
            float4 q = ((const float4*)(cb + ((size_t)bidS * NG + g) * ND))[tid];
            ((float4*)(out_q + (size_t)idx * ND))[tid] = q;
            float4 a = ((const float4*)xs)[tid];
            float e0 = q.x - a.x, e1 = q.y - a.y;
            float e2 = q.z - a.z, e3 = q.w - a.w;
            float s = e0 * e0 + e1 * e1 + e2 * e2 + e3 * e3;
#pragma unroll
            for (int m = 1; m < 32; m <<= 1) s += __shfl_xor(s, m);
            if (tid == 0) lossg[idx] = s;
        }
    }
}

// ---------------------------------------------------------------------------
__global__ __launch_bounds__(256) void loss_part(
    const float* __restrict__ lossg, float* __restrict__ part) {
    __shared__ float sr[256];
    const int tid = threadIdx.x;
    float4 v = ((const float4*)lossg)[blockIdx.x * 256 + tid];
    sr[tid] = ((v.x + v.y) + (v.z + v.w));
    __syncthreads();
    for (int st = 128; st > 0; st >>= 1) {
        if (tid < st) sr[tid] += sr[tid + st];
        __syncthreads();
    }
    if (tid == 0) part[blockIdx.x] = sr[0];
}

// ---------------------------------------------------------------------------
// final: msum = cnt[1] (token count from compaction); 64-lane tree sum.
// ---------------------------------------------------------------------------
__global__ __launch_bounds__(64) void final_kernel(
    const int* __restrict__ cnt, const float* __restrict__ part,
    float* __restrict__ out_l) {
    const int tid = threadIdx.x;
    float s = part[tid];
#pragma unroll
    for (int m = 1; m < 64; m <<= 1) s += __shfl_xor(s, m);
    if (tid == 0) {
        float k = s / (float)cnt[1];
        out_l[0] = k;
        out_l[1] = k;
        out_l[2] = k + k;
    }
}

// ---------------------------------------------------------------------------
extern "C" void kernel_launch(void* const* d_in, const int* in_sizes, int n_in,
                              void* d_out, int out_size, void* d_ws, size_t ws_size,
                              hipStream_t stream) {
    const float* x = (const float*)d_in[0];
    const int* pad = (const int*)d_in[1];
    const float* cb = (const float*)d_in[2];
    float* out = (float*)d_out;
    float* ws = (float*)d_ws;

    float* ws_c2a = ws + OFF_C2A;
    float* ws_c2b = ws + OFF_C2B;
    float* ws_lossg = ws + OFF_LOSSG;
    int* ws_cnt = (int*)(ws + OFF_CNT);      // [0]=flag cnt, [1]=token cnt
    int* ws_flags = (int*)(ws + OFF_FLAGS);
    f16* cbh = (f16*)(ws + OFF_CBH);
    float* ws_part = ws + OFF_PART;
    int* ws_cand2 = (int*)(ws + OFF_CAND2);
    int* ws_tokmap = (int*)(ws + OFF_TOKMAP);

    prep_kernel<<<1025, 256, 0, stream>>>(cb, pad, cbh, ws_c2a, ws_c2b,
                                          ws_cnt, ws_tokmap, out + OUT_IDS,
                                          out + OUT_Q, ws_lossg);
    mfma_gemm<<<(BT / BM) * NG, 256, 0, stream>>>(x, cbh, cb, ws_c2b,
                                                  ws_cnt + 1, ws_tokmap,
                                                  out + OUT_IDS, out + OUT_Q,
                                                  ws_lossg, ws_cnt, ws_flags,
                                                  ws_cand2);
    recheck<<<512, 256, 0, stream>>>(x, cb, ws_c2a, ws_cnt, ws_flags,
                                     ws_cand2, out + OUT_IDS, out + OUT_Q,
                                     ws_lossg);
    loss_part<<<64, 256, 0, stream>>>(ws_lossg, ws_part);
    final_kernel<<<1, 64, 0, stream>>>(ws_cnt, ws_part, out + OUT_L);
}